// Round 11
// baseline (71.043 us; speedup 1.0000x reference)
//
#include <hip/hip_runtime.h>
#include <stdint.h>

#define BATCH 16
#define NPTS  4096
#define TOT   (BATCH * NPTS)     // 65536 points per tensor
#define TWOTOT (2 * TOT)

typedef float f4 __attribute__((ext_vector_type(4)));
typedef uint32_t u32;
typedef unsigned long long u64;

// ---- scalar fp32 math (2cy/instr; packed VOP3P f32 measured at 8cy = 2x slower) ----
// broadcast one SGPR (q.w) into a VGPR, once per Q point
#define MOVQW(qwv, qq) \
    asm("v_mov_b32 %0, %1" : "=v"(qwv) : "s"(qq.w))
// d = pz*qz + qw ; d += py*qy ; d += px*qx   (exactly 1 SGPR per instr)
#define DIST1(d, pxv, pyv, pzv, qq, qwv)                                    \
    do {                                                                    \
        asm("v_fma_f32 %0, %1, %2, %3"                                      \
            : "=v"(d) : "v"(pzv), "s"(qq.z), "v"(qwv));                     \
        asm("v_fmac_f32 %0, %1, %2" : "+v"(d) : "s"(qq.y), "v"(pyv));       \
        asm("v_fmac_f32 %0, %1, %2" : "+v"(d) : "s"(qq.x), "v"(pxv));       \
    } while (0)
#define MIN3(acc, u, v) \
    asm("v_min3_f32 %0, %1, %2, %0" : "+v"(acc) : "v"(u), "v"(v))

// 2 Q points vs the thread's 8 P points:
// 2 mov + 48 fma + 8 min3 = 58 instr = 116 cy per 1024 pair-evals
#define COMP2S(qA, qB)                                                      \
    do {                                                                    \
        float qwA, qwB;                                                     \
        MOVQW(qwA, qA); MOVQW(qwB, qB);                                     \
        float dA0, dA1, dA2, dA3, dA4, dA5, dA6, dA7;                       \
        float dB0, dB1, dB2, dB3, dB4, dB5, dB6, dB7;                       \
        DIST1(dA0, nx0, ny0, nz0, qA, qwA); DIST1(dB0, nx0, ny0, nz0, qB, qwB); \
        DIST1(dA1, nx1, ny1, nz1, qA, qwA); DIST1(dB1, nx1, ny1, nz1, qB, qwB); \
        DIST1(dA2, nx2, ny2, nz2, qA, qwA); DIST1(dB2, nx2, ny2, nz2, qB, qwB); \
        DIST1(dA3, nx3, ny3, nz3, qA, qwA); DIST1(dB3, nx3, ny3, nz3, qB, qwB); \
        DIST1(dA4, nx4, ny4, nz4, qA, qwA); DIST1(dB4, nx4, ny4, nz4, qB, qwB); \
        DIST1(dA5, nx5, ny5, nz5, qA, qwA); DIST1(dB5, nx5, ny5, nz5, qB, qwB); \
        DIST1(dA6, nx6, ny6, nz6, qA, qwA); DIST1(dB6, nx6, ny6, nz6, qB, qwB); \
        DIST1(dA7, nx7, ny7, nz7, qA, qwA); DIST1(dB7, nx7, ny7, nz7, qB, qwB); \
        MIN3(acc0, dA0, dB0); MIN3(acc1, dA1, dB1);                         \
        MIN3(acc2, dA2, dB2); MIN3(acc3, dA3, dB3);                         \
        MIN3(acc4, dA4, dB4); MIN3(acc5, dA5, dB5);                         \
        MIN3(acc6, dA6, dB6); MIN3(acc7, dA7, dB7);                         \
    } while (0)

#define COMP8S(q0, q1, q2, q3, q4, q5, q6, q7)                  \
    do { COMP2S(q0, q1); COMP2S(q2, q3); COMP2S(q4, q5); COMP2S(q6, q7); } while (0)

// one scalar load of one Q point (16B) at qb + imm
#define SL(dst, imm) \
    asm volatile("s_load_dwordx4 %0, %1, " imm : "=s"(dst) : "s"(qb))

// issue one 8-point chunk (128B), bump base, pin issue point
#define SLOAD8(n0, n1, n2, n3, n4, n5, n6, n7)                  \
    do {                                                        \
        SL(n0, "0x0");  SL(n1, "0x10"); SL(n2, "0x20"); SL(n3, "0x30"); \
        SL(n4, "0x40"); SL(n5, "0x50"); SL(n6, "0x60"); SL(n7, "0x70"); \
        qb += 128;                                              \
        __builtin_amdgcn_sched_barrier(0);                      \
    } while (0)

// drain SMEM (OOO completion -> only lgkmcnt(0) safe); ties the chunk so
// dependent math can't hoist; sched_barrier fences (rule #18).
#define LGKMW8(a0, a1, a2, a3, a4, a5, a6, a7)                  \
    do {                                                        \
        asm volatile("s_waitcnt lgkmcnt(0)"                     \
            : "+s"(a0), "+s"(a1), "+s"(a2), "+s"(a3),           \
              "+s"(a4), "+s"(a5), "+s"(a6), "+s"(a7));          \
        __builtin_amdgcn_sched_barrier(0);                      \
    } while (0)

// Pack {x, y, z, |q|^2} AoS float4 per point; also zero the output scalar.
// pk layout: [2][BATCH][NPTS] f4 ; slot 0 = x tensor, slot 1 = y tensor.
__global__ __launch_bounds__(256) void pack_kernel(const float* __restrict__ x,
                                                   const float* __restrict__ y,
                                                   f4* __restrict__ pk,
                                                   float* __restrict__ out) {
    int idx = blockIdx.x * 256 + threadIdx.x;       // 0 .. 2*TOT-1
    if (idx == 0) out[0] = 0.0f;
    const float* src = (idx < TOT) ? x : y;
    int r = (idx < TOT) ? idx : (idx - TOT);
    float a = src[r * 3 + 0];
    float b = src[r * 3 + 1];
    float c = src[r * 3 + 2];
    f4 v = {a, b, c, fmaf(a, a, fmaf(b, b, c * c))};
    pk[idx] = v;
}

// Pass 1: each thread owns EIGHT consecutive P points; Q streams through
// SGPRs (s_load_dwordx4, fetched once per wave). 2-bank 8-Q chunks, proven
// stall-free in R9/R10. Math is scalar fma/fmac/min3 at 2cy each.
template <int QSEGT>
__global__ __launch_bounds__(256) void chamfer_pass1(const f4* __restrict__ pk,
                                                     float* __restrict__ part) {
    constexpr int QLENT  = NPTS / QSEGT;
    constexpr int CHUNKS = QLENT / 8;         // even

    int qseg  = blockIdx.x & (QSEGT - 1);
    int chunk = blockIdx.x / QSEGT;           // 64 chunks of 2048 P points

    // block-uniform (from blockIdx only) -> SALU
    int grp   = chunk >> 1;                   // dir*16 + batch
    int dir   = grp >> 4;
    int bb    = grp & 15;

    int pidx0 = chunk * 2048 + threadIdx.x * 8;

    f4 p0 = pk[pidx0 + 0], p1 = pk[pidx0 + 1];
    f4 p2 = pk[pidx0 + 2], p3 = pk[pidx0 + 3];
    f4 p4 = pk[pidx0 + 4], p5 = pk[pidx0 + 5];
    f4 p6 = pk[pidx0 + 6], p7 = pk[pidx0 + 7];
    float nx0 = -2.0f * p0.x, ny0 = -2.0f * p0.y, nz0 = -2.0f * p0.z;
    float nx1 = -2.0f * p1.x, ny1 = -2.0f * p1.y, nz1 = -2.0f * p1.z;
    float nx2 = -2.0f * p2.x, ny2 = -2.0f * p2.y, nz2 = -2.0f * p2.z;
    float nx3 = -2.0f * p3.x, ny3 = -2.0f * p3.y, nz3 = -2.0f * p3.z;
    float nx4 = -2.0f * p4.x, ny4 = -2.0f * p4.y, nz4 = -2.0f * p4.z;
    float nx5 = -2.0f * p5.x, ny5 = -2.0f * p5.y, nz5 = -2.0f * p5.z;
    float nx6 = -2.0f * p6.x, ny6 = -2.0f * p6.y, nz6 = -2.0f * p6.z;
    float nx7 = -2.0f * p7.x, ny7 = -2.0f * p7.y, nz7 = -2.0f * p7.z;
    asm volatile("" :: "v"(nx0), "v"(ny0), "v"(nz0), "v"(nx1), "v"(ny1), "v"(nz1),
                       "v"(nx2), "v"(ny2), "v"(nz2), "v"(nx3), "v"(ny3), "v"(nz3),
                       "v"(nx4), "v"(ny4), "v"(nz4), "v"(nx5), "v"(ny5), "v"(nz5),
                       "v"(nx6), "v"(ny6), "v"(nz6), "v"(nx7), "v"(ny7), "v"(nz7));
    __builtin_amdgcn_sched_barrier(0);

    // uniform 64-bit Q base in SGPRs
    union { const f4* p; u32 w[2]; } pu;
    pu.p = pk + (1 - dir) * TOT + bb * NPTS + qseg * QLENT;
    u32 w0 = __builtin_amdgcn_readfirstlane(pu.w[0]);
    u32 w1 = __builtin_amdgcn_readfirstlane(pu.w[1]);
    u64 qb = ((u64)w1 << 32) | w0;

    float acc0 = 3.4e38f, acc1 = 3.4e38f, acc2 = 3.4e38f, acc3 = 3.4e38f;
    float acc4 = 3.4e38f, acc5 = 3.4e38f, acc6 = 3.4e38f, acc7 = 3.4e38f;

    f4 c0, c1, c2, c3, c4, c5, c6, c7;        // current bank (SGPRs)
    f4 n0, n1, n2, n3, n4, n5, n6, n7;        // next bank (SGPRs)

    SLOAD8(c0, c1, c2, c3, c4, c5, c6, c7);   // chunk 0
    LGKMW8(c0, c1, c2, c3, c4, c5, c6, c7);

    #pragma unroll 1
    for (int it = 0; it < (CHUNKS - 2) / 2; ++it) {
        SLOAD8(n0, n1, n2, n3, n4, n5, n6, n7);      // chunk 2it+1
        COMP8S(c0, c1, c2, c3, c4, c5, c6, c7);      // chunk 2it
        LGKMW8(n0, n1, n2, n3, n4, n5, n6, n7);
        SLOAD8(c0, c1, c2, c3, c4, c5, c6, c7);      // chunk 2it+2
        COMP8S(n0, n1, n2, n3, n4, n5, n6, n7);      // chunk 2it+1
        LGKMW8(c0, c1, c2, c3, c4, c5, c6, c7);
    }
    SLOAD8(n0, n1, n2, n3, n4, n5, n6, n7);          // chunk CHUNKS-1
    COMP8S(c0, c1, c2, c3, c4, c5, c6, c7);          // chunk CHUNKS-2
    LGKMW8(n0, n1, n2, n3, n4, n5, n6, n7);
    COMP8S(n0, n1, n2, n3, n4, n5, n6, n7);          // chunk CHUNKS-1

    f4 lo = {acc0, acc1, acc2, acc3};
    f4 hi = {acc4, acc5, acc6, acc7};
    f4* dst = (f4*)(part + qseg * TWOTOT + pidx0);
    dst[0] = lo;
    dst[1] = hi;
}

// Pass 2: 4 points per thread, f4 loads of the partials, add |p|^2,
// block-reduce, one atomic per block.
__global__ __launch_bounds__(256) void chamfer_pass2(const f4* __restrict__ part4,
                                                     const float* __restrict__ pkf,
                                                     float* __restrict__ out,
                                                     int nseg) {
    int t4  = blockIdx.x * 256 + threadIdx.x;     // 0..TWOTOT/4-1
    f4 m = part4[t4];
    for (int s = 1; s < nseg; ++s) {
        f4 v = part4[s * (TWOTOT / 4) + t4];
        m.x = fminf(m.x, v.x); m.y = fminf(m.y, v.y);
        m.z = fminf(m.z, v.z); m.w = fminf(m.w, v.w);
    }
    int gid = t4 * 4;
    float r = (m.x + pkf[(gid + 0) * 4 + 3]) + (m.y + pkf[(gid + 1) * 4 + 3])
            + (m.z + pkf[(gid + 2) * 4 + 3]) + (m.w + pkf[(gid + 3) * 4 + 3]);

    float s = r;
    #pragma unroll
    for (int off = 32; off; off >>= 1) s += __shfl_down(s, off);
    __shared__ float red[4];
    int lane = threadIdx.x & 63, wid = threadIdx.x >> 6;
    if (lane == 0) red[wid] = s;
    __syncthreads();
    if (threadIdx.x == 0) {
        float tot = (red[0] + red[1]) + (red[2] + red[3]);
        atomicAdd(out, tot * (1.0f / (float)TOT));
    }
}

// ---------------- fallback (no workspace): direct form ----------------
__global__ __launch_bounds__(256) void chamfer_direct(const float* __restrict__ x,
                                                      const float* __restrict__ y,
                                                      float* __restrict__ out) {
    int blk   = blockIdx.x;
    int dir   = blk >> 8;
    int t     = blk & 255;
    int b     = t >> 4;
    int chunk = t & 15;

    const float* __restrict__ P = (dir ? y : x) + (b * NPTS + chunk * 256) * 3;
    const float* __restrict__ Q = (dir ? x : y) + b * NPTS * 3;

    float px = P[threadIdx.x * 3 + 0];
    float py = P[threadIdx.x * 3 + 1];
    float pz = P[threadIdx.x * 3 + 2];

    float b0 = 3.4e38f, b1 = 3.4e38f, b2 = 3.4e38f, b3 = 3.4e38f;
    for (int j = 0; j < NPTS; j += 4) {
        #pragma unroll
        for (int u = 0; u < 4; ++u) {
            float dx = px - Q[(j + u) * 3 + 0];
            float dy = py - Q[(j + u) * 3 + 1];
            float dz = pz - Q[(j + u) * 3 + 2];
            float d  = fmaf(dx, dx, fmaf(dy, dy, dz * dz));
            if (u == 0) b0 = fminf(b0, d);
            if (u == 1) b1 = fminf(b1, d);
            if (u == 2) b2 = fminf(b2, d);
            if (u == 3) b3 = fminf(b3, d);
        }
    }
    float best = fminf(fminf(b0, b1), fminf(b2, b3));

    float v = best;
    #pragma unroll
    for (int off = 32; off; off >>= 1) v += __shfl_down(v, off);
    __shared__ float red[4];
    int lane = threadIdx.x & 63, wid = threadIdx.x >> 6;
    if (lane == 0) red[wid] = v;
    __syncthreads();
    if (threadIdx.x == 0) {
        float s = (red[0] + red[1]) + (red[2] + red[3]);
        atomicAdd(out, s * (1.0f / (float)TOT));
    }
}

__global__ void zero_kernel(float* out) { out[0] = 0.0f; }

extern "C" void kernel_launch(void* const* d_in, const int* in_sizes, int n_in,
                              void* d_out, int out_size, void* d_ws, size_t ws_size,
                              hipStream_t stream) {
    const float* x = (const float*)d_in[0];
    const float* y = (const float*)d_in[1];
    float* out = (float*)d_out;

    size_t pk_bytes = (size_t)TWOTOT * 4 * sizeof(float);         // 2 MiB
    auto part_bytes = [&](int qseg) { return (size_t)qseg * TWOTOT * sizeof(float); };

    if (ws_size >= pk_bytes + part_bytes(16)) {
        // QSEG = 16 : grid 1024 (4 blocks/CU), part 8 MiB
        float* pkf  = (float*)d_ws;
        float* part = (float*)((char*)d_ws + pk_bytes);
        hipLaunchKernelGGL(pack_kernel, dim3(TWOTOT / 256), dim3(256), 0, stream,
                           x, y, (f4*)pkf, out);
        hipLaunchKernelGGL((chamfer_pass1<16>), dim3(64 * 16), dim3(256), 0, stream,
                           (const f4*)pkf, part);
        hipLaunchKernelGGL(chamfer_pass2, dim3(TWOTOT / 4 / 256), dim3(256), 0, stream,
                           (const f4*)part, pkf, out, 16);
    } else if (ws_size >= pk_bytes + part_bytes(8)) {
        // QSEG = 8 : grid 512, part 4 MiB
        float* pkf  = (float*)d_ws;
        float* part = (float*)((char*)d_ws + pk_bytes);
        hipLaunchKernelGGL(pack_kernel, dim3(TWOTOT / 256), dim3(256), 0, stream,
                           x, y, (f4*)pkf, out);
        hipLaunchKernelGGL((chamfer_pass1<8>), dim3(64 * 8), dim3(256), 0, stream,
                           (const f4*)pkf, part);
        hipLaunchKernelGGL(chamfer_pass2, dim3(TWOTOT / 4 / 256), dim3(256), 0, stream,
                           (const f4*)part, pkf, out, 8);
    } else if (ws_size >= pk_bytes + part_bytes(4)) {
        // QSEG = 4 : grid 256, part 2 MiB
        float* pkf  = (float*)d_ws;
        float* part = (float*)((char*)d_ws + pk_bytes);
        hipLaunchKernelGGL(pack_kernel, dim3(TWOTOT / 256), dim3(256), 0, stream,
                           x, y, (f4*)pkf, out);
        hipLaunchKernelGGL((chamfer_pass1<4>), dim3(64 * 4), dim3(256), 0, stream,
                           (const f4*)pkf, part);
        hipLaunchKernelGGL(chamfer_pass2, dim3(TWOTOT / 4 / 256), dim3(256), 0, stream,
                           (const f4*)part, pkf, out, 4);
    } else {
        hipLaunchKernelGGL(zero_kernel, dim3(1), dim3(1), 0, stream, out);
        hipLaunchKernelGGL(chamfer_direct, dim3(512), dim3(256), 0, stream, x, y, out);
    }
}

// Round 12
// 59.778 us; speedup vs baseline: 1.1884x; 1.1884x over previous
//
#include <hip/hip_runtime.h>
#include <stdint.h>

#define BATCH 16
#define NPTS  4096
#define TOT   (BATCH * NPTS)     // 65536 points per tensor
#define TWOTOT (2 * TOT)

typedef float f4 __attribute__((ext_vector_type(4)));
typedef uint32_t u32;

// ---- scalar fp32 math, all-VGPR operands, interleaved chains ----
// step1: d = pz*q.z + q.w
#define FMA1(d, pz, q) \
    asm("v_fma_f32 %0, %1, %2, %3" : "=v"(d) : "v"(pz), "v"(q.z), "v"(q.w))
// step2/3: d += c * q.comp
#define FMACY(d, py, q) \
    asm("v_fmac_f32 %0, %1, %2" : "+v"(d) : "v"(py), "v"(q.y))
#define FMACX(d, px, q) \
    asm("v_fmac_f32 %0, %1, %2" : "+v"(d) : "v"(px), "v"(q.x))
#define MIN3(acc, u, v) \
    asm("v_min3_f32 %0, %1, %2, %0" : "+v"(acc) : "v"(u), "v"(v))

// 2 Q points (VGPR-broadcast) vs the thread's 8 P points.
// Emission order: 16x step1, 16x step2, 16x step3, 8x min3 -> dependent ops
// are ~15 instrs apart, zero hazard bubbles. 56 instrs per 16 pair-evals.
#define COMP2V(qA, qB)                                                      \
    do {                                                                    \
        float dA0, dA1, dA2, dA3, dA4, dA5, dA6, dA7;                       \
        float dB0, dB1, dB2, dB3, dB4, dB5, dB6, dB7;                       \
        FMA1(dA0, nz0, qA); FMA1(dB0, nz0, qB);                             \
        FMA1(dA1, nz1, qA); FMA1(dB1, nz1, qB);                             \
        FMA1(dA2, nz2, qA); FMA1(dB2, nz2, qB);                             \
        FMA1(dA3, nz3, qA); FMA1(dB3, nz3, qB);                             \
        FMA1(dA4, nz4, qA); FMA1(dB4, nz4, qB);                             \
        FMA1(dA5, nz5, qA); FMA1(dB5, nz5, qB);                             \
        FMA1(dA6, nz6, qA); FMA1(dB6, nz6, qB);                             \
        FMA1(dA7, nz7, qA); FMA1(dB7, nz7, qB);                             \
        FMACY(dA0, ny0, qA); FMACY(dB0, ny0, qB);                           \
        FMACY(dA1, ny1, qA); FMACY(dB1, ny1, qB);                           \
        FMACY(dA2, ny2, qA); FMACY(dB2, ny2, qB);                           \
        FMACY(dA3, ny3, qA); FMACY(dB3, ny3, qB);                           \
        FMACY(dA4, ny4, qA); FMACY(dB4, ny4, qB);                           \
        FMACY(dA5, ny5, qA); FMACY(dB5, ny5, qB);                           \
        FMACY(dA6, ny6, qA); FMACY(dB6, ny6, qB);                           \
        FMACY(dA7, ny7, qA); FMACY(dB7, ny7, qB);                           \
        FMACX(dA0, nx0, qA); FMACX(dB0, nx0, qB);                           \
        FMACX(dA1, nx1, qA); FMACX(dB1, nx1, qB);                           \
        FMACX(dA2, nx2, qA); FMACX(dB2, nx2, qB);                           \
        FMACX(dA3, nx3, qA); FMACX(dB3, nx3, qB);                           \
        FMACX(dA4, nx4, qA); FMACX(dB4, nx4, qB);                           \
        FMACX(dA5, nx5, qA); FMACX(dB5, nx5, qB);                           \
        FMACX(dA6, nx6, qA); FMACX(dB6, nx6, qB);                           \
        FMACX(dA7, nx7, qA); FMACX(dB7, nx7, qB);                           \
        MIN3(acc0, dA0, dB0); MIN3(acc1, dA1, dB1);                         \
        MIN3(acc2, dA2, dB2); MIN3(acc3, dA3, dB3);                         \
        MIN3(acc4, dA4, dB4); MIN3(acc5, dA5, dB5);                         \
        MIN3(acc6, dA6, dB6); MIN3(acc7, dA7, dB7);                         \
    } while (0)

// uniform-address LDS broadcast read of one Q point (16B). LDS completes
// IN ORDER -> counted lgkmcnt waits are safe (unlike SMEM).
#define DSR(dst, imm) \
    asm volatile("ds_read_b128 %0, %1 offset:" imm : "=v"(dst) : "v"(lofs))

// counted wait: only the oldest 2 of 16 outstanding ds_reads; ties the two
// slots so dependent math can't hoist; sched_barrier fences (rule #18).
#define WAITL(cnt, qa, qb)                                      \
    do {                                                        \
        asm volatile("s_waitcnt lgkmcnt(" cnt ")"               \
                     : "+v"(qa), "+v"(qb));                     \
        __builtin_amdgcn_sched_barrier(0);                      \
    } while (0)

// steady step: wait oldest 2, compute them, reissue those slots from the
// next group's LDS offsets
#define STEPV(qa, qb, immA, immB)                               \
    do {                                                        \
        WAITL("14", qa, qb);                                    \
        COMP2V(qa, qb);                                         \
        DSR(qa, immA); DSR(qb, immB);                           \
    } while (0)

#define STEPD(cnt, qa, qb)  do { WAITL(cnt, qa, qb); COMP2V(qa, qb); } while (0)

// Pack {x, y, z, |q|^2} AoS float4 per point; also zero the output scalar.
// pk layout: [2][BATCH][NPTS] f4 ; slot 0 = x tensor, slot 1 = y tensor.
__global__ __launch_bounds__(256) void pack_kernel(const float* __restrict__ x,
                                                   const float* __restrict__ y,
                                                   f4* __restrict__ pk,
                                                   float* __restrict__ out) {
    int idx = blockIdx.x * 256 + threadIdx.x;       // 0 .. 2*TOT-1
    if (idx == 0) out[0] = 0.0f;
    const float* src = (idx < TOT) ? x : y;
    int r = (idx < TOT) ? idx : (idx - TOT);
    float a = src[r * 3 + 0];
    float b = src[r * 3 + 1];
    float c = src[r * 3 + 2];
    f4 v = {a, b, c, fmaf(a, a, fmaf(b, b, c * c))};
    pk[idx] = v;
}

// Pass 1: each thread owns 8 consecutive P points. The block's Q segment is
// staged once into LDS (4KB at QSEG=16); the loop streams it via uniform
// ds_read_b128 broadcasts through a 16-slot rotating pipeline with counted
// lgkmcnt(14) waits (LDS is in-order). Math: interleaved scalar fma @2cy.
template <int QSEGT>
__global__ __launch_bounds__(256) void chamfer_pass1(const f4* __restrict__ pk,
                                                     float* __restrict__ part) {
    constexpr int QLENT = NPTS / QSEGT;
    constexpr int NGRP  = QLENT / 16;         // 16-Q groups per segment

    __shared__ f4 qlds[QLENT];

    int qseg  = blockIdx.x & (QSEGT - 1);
    int chunk = blockIdx.x / QSEGT;           // 64 chunks of 2048 P points

    // block-uniform (from blockIdx only)
    int grp   = chunk >> 1;                   // dir*16 + batch
    int dir   = grp >> 4;
    int bb    = grp & 15;

    // stage Q segment into LDS (once)
    const f4* __restrict__ qsrc = pk + (1 - dir) * TOT + bb * NPTS + qseg * QLENT;
    for (int i = threadIdx.x; i < QLENT; i += 256) qlds[i] = qsrc[i];

    int pidx0 = chunk * 2048 + threadIdx.x * 8;
    f4 p0 = pk[pidx0 + 0], p1 = pk[pidx0 + 1];
    f4 p2 = pk[pidx0 + 2], p3 = pk[pidx0 + 3];
    f4 p4 = pk[pidx0 + 4], p5 = pk[pidx0 + 5];
    f4 p6 = pk[pidx0 + 6], p7 = pk[pidx0 + 7];
    float nx0 = -2.0f * p0.x, ny0 = -2.0f * p0.y, nz0 = -2.0f * p0.z;
    float nx1 = -2.0f * p1.x, ny1 = -2.0f * p1.y, nz1 = -2.0f * p1.z;
    float nx2 = -2.0f * p2.x, ny2 = -2.0f * p2.y, nz2 = -2.0f * p2.z;
    float nx3 = -2.0f * p3.x, ny3 = -2.0f * p3.y, nz3 = -2.0f * p3.z;
    float nx4 = -2.0f * p4.x, ny4 = -2.0f * p4.y, nz4 = -2.0f * p4.z;
    float nx5 = -2.0f * p5.x, ny5 = -2.0f * p5.y, nz5 = -2.0f * p5.z;
    float nx6 = -2.0f * p6.x, ny6 = -2.0f * p6.y, nz6 = -2.0f * p6.z;
    float nx7 = -2.0f * p7.x, ny7 = -2.0f * p7.y, nz7 = -2.0f * p7.z;

    __syncthreads();   // staging complete; drains staging lgkm/vm counts

    float acc0 = 3.4e38f, acc1 = 3.4e38f, acc2 = 3.4e38f, acc3 = 3.4e38f;
    float acc4 = 3.4e38f, acc5 = 3.4e38f, acc6 = 3.4e38f, acc7 = 3.4e38f;

    u32 lofs = (u32)(uintptr_t)&qlds[0];      // LDS byte offset of segment base

    f4 s0, s1, s2, s3, s4, s5, s6, s7, s8, s9, s10, s11, s12, s13, s14, s15;
    // prologue: issue reads for group 0 (16 points, offsets 0..240)
    DSR(s0, "0");    DSR(s1, "16");   DSR(s2, "32");   DSR(s3, "48");
    DSR(s4, "64");   DSR(s5, "80");   DSR(s6, "96");   DSR(s7, "112");
    DSR(s8, "128");  DSR(s9, "144");  DSR(s10, "160"); DSR(s11, "176");
    DSR(s12, "192"); DSR(s13, "208"); DSR(s14, "224"); DSR(s15, "240");
    lofs += 256;                               // prefetch base = group 1

    #pragma unroll 1
    for (int g = 0; g < NGRP - 1; ++g) {
        STEPV(s0,  s1,  "0",   "16");
        STEPV(s2,  s3,  "32",  "48");
        STEPV(s4,  s5,  "64",  "80");
        STEPV(s6,  s7,  "96",  "112");
        STEPV(s8,  s9,  "128", "144");
        STEPV(s10, s11, "160", "176");
        STEPV(s12, s13, "192", "208");
        STEPV(s14, s15, "224", "240");
        lofs += 256;
    }
    // drain the last group
    STEPD("14", s0,  s1);
    STEPD("12", s2,  s3);
    STEPD("10", s4,  s5);
    STEPD("8",  s6,  s7);
    STEPD("6",  s8,  s9);
    STEPD("4",  s10, s11);
    STEPD("2",  s12, s13);
    STEPD("0",  s14, s15);

    f4 lo = {acc0, acc1, acc2, acc3};
    f4 hi = {acc4, acc5, acc6, acc7};
    f4* dst = (f4*)(part + qseg * TWOTOT + pidx0);
    dst[0] = lo;
    dst[1] = hi;
}

// Pass 2: 4 points per thread, f4 loads of the partials, add |p|^2,
// block-reduce, one atomic per block.
__global__ __launch_bounds__(256) void chamfer_pass2(const f4* __restrict__ part4,
                                                     const float* __restrict__ pkf,
                                                     float* __restrict__ out,
                                                     int nseg) {
    int t4  = blockIdx.x * 256 + threadIdx.x;     // 0..TWOTOT/4-1
    f4 m = part4[t4];
    for (int s = 1; s < nseg; ++s) {
        f4 v = part4[s * (TWOTOT / 4) + t4];
        m.x = fminf(m.x, v.x); m.y = fminf(m.y, v.y);
        m.z = fminf(m.z, v.z); m.w = fminf(m.w, v.w);
    }
    int gid = t4 * 4;
    float r = (m.x + pkf[(gid + 0) * 4 + 3]) + (m.y + pkf[(gid + 1) * 4 + 3])
            + (m.z + pkf[(gid + 2) * 4 + 3]) + (m.w + pkf[(gid + 3) * 4 + 3]);

    float s = r;
    #pragma unroll
    for (int off = 32; off; off >>= 1) s += __shfl_down(s, off);
    __shared__ float red[4];
    int lane = threadIdx.x & 63, wid = threadIdx.x >> 6;
    if (lane == 0) red[wid] = s;
    __syncthreads();
    if (threadIdx.x == 0) {
        float tot = (red[0] + red[1]) + (red[2] + red[3]);
        atomicAdd(out, tot * (1.0f / (float)TOT));
    }
}

// ---------------- fallback (no workspace): direct form ----------------
__global__ __launch_bounds__(256) void chamfer_direct(const float* __restrict__ x,
                                                      const float* __restrict__ y,
                                                      float* __restrict__ out) {
    int blk   = blockIdx.x;
    int dir   = blk >> 8;
    int t     = blk & 255;
    int b     = t >> 4;
    int chunk = t & 15;

    const float* __restrict__ P = (dir ? y : x) + (b * NPTS + chunk * 256) * 3;
    const float* __restrict__ Q = (dir ? x : y) + b * NPTS * 3;

    float px = P[threadIdx.x * 3 + 0];
    float py = P[threadIdx.x * 3 + 1];
    float pz = P[threadIdx.x * 3 + 2];

    float b0 = 3.4e38f, b1 = 3.4e38f, b2 = 3.4e38f, b3 = 3.4e38f;
    for (int j = 0; j < NPTS; j += 4) {
        #pragma unroll
        for (int u = 0; u < 4; ++u) {
            float dx = px - Q[(j + u) * 3 + 0];
            float dy = py - Q[(j + u) * 3 + 1];
            float dz = pz - Q[(j + u) * 3 + 2];
            float d  = fmaf(dx, dx, fmaf(dy, dy, dz * dz));
            if (u == 0) b0 = fminf(b0, d);
            if (u == 1) b1 = fminf(b1, d);
            if (u == 2) b2 = fminf(b2, d);
            if (u == 3) b3 = fminf(b3, d);
        }
    }
    float best = fminf(fminf(b0, b1), fminf(b2, b3));

    float v = best;
    #pragma unroll
    for (int off = 32; off; off >>= 1) v += __shfl_down(v, off);
    __shared__ float red[4];
    int lane = threadIdx.x & 63, wid = threadIdx.x >> 6;
    if (lane == 0) red[wid] = v;
    __syncthreads();
    if (threadIdx.x == 0) {
        float s = (red[0] + red[1]) + (red[2] + red[3]);
        atomicAdd(out, s * (1.0f / (float)TOT));
    }
}

__global__ void zero_kernel(float* out) { out[0] = 0.0f; }

extern "C" void kernel_launch(void* const* d_in, const int* in_sizes, int n_in,
                              void* d_out, int out_size, void* d_ws, size_t ws_size,
                              hipStream_t stream) {
    const float* x = (const float*)d_in[0];
    const float* y = (const float*)d_in[1];
    float* out = (float*)d_out;

    size_t pk_bytes = (size_t)TWOTOT * 4 * sizeof(float);         // 2 MiB
    auto part_bytes = [&](int qseg) { return (size_t)qseg * TWOTOT * sizeof(float); };

    if (ws_size >= pk_bytes + part_bytes(16)) {
        // QSEG = 16 : grid 1024 (4 blocks/CU), part 8 MiB, LDS 4KB/block
        float* pkf  = (float*)d_ws;
        float* part = (float*)((char*)d_ws + pk_bytes);
        hipLaunchKernelGGL(pack_kernel, dim3(TWOTOT / 256), dim3(256), 0, stream,
                           x, y, (f4*)pkf, out);
        hipLaunchKernelGGL((chamfer_pass1<16>), dim3(64 * 16), dim3(256), 0, stream,
                           (const f4*)pkf, part);
        hipLaunchKernelGGL(chamfer_pass2, dim3(TWOTOT / 4 / 256), dim3(256), 0, stream,
                           (const f4*)part, pkf, out, 16);
    } else if (ws_size >= pk_bytes + part_bytes(8)) {
        // QSEG = 8 : grid 512, part 4 MiB, LDS 8KB/block
        float* pkf  = (float*)d_ws;
        float* part = (float*)((char*)d_ws + pk_bytes);
        hipLaunchKernelGGL(pack_kernel, dim3(TWOTOT / 256), dim3(256), 0, stream,
                           x, y, (f4*)pkf, out);
        hipLaunchKernelGGL((chamfer_pass1<8>), dim3(64 * 8), dim3(256), 0, stream,
                           (const f4*)pkf, part);
        hipLaunchKernelGGL(chamfer_pass2, dim3(TWOTOT / 4 / 256), dim3(256), 0, stream,
                           (const f4*)part, pkf, out, 8);
    } else if (ws_size >= pk_bytes + part_bytes(4)) {
        // QSEG = 4 : grid 256, part 2 MiB, LDS 16KB/block
        float* pkf  = (float*)d_ws;
        float* part = (float*)((char*)d_ws + pk_bytes);
        hipLaunchKernelGGL(pack_kernel, dim3(TWOTOT / 256), dim3(256), 0, stream,
                           x, y, (f4*)pkf, out);
        hipLaunchKernelGGL((chamfer_pass1<4>), dim3(64 * 4), dim3(256), 0, stream,
                           (const f4*)pkf, part);
        hipLaunchKernelGGL(chamfer_pass2, dim3(TWOTOT / 4 / 256), dim3(256), 0, stream,
                           (const f4*)part, pkf, out, 4);
    } else {
        hipLaunchKernelGGL(zero_kernel, dim3(1), dim3(1), 0, stream, out);
        hipLaunchKernelGGL(chamfer_direct, dim3(512), dim3(256), 0, stream, x, y, out);
    }
}